// Round 1
// baseline (1295.591 us; speedup 1.0000x reference)
//
#include <hip/hip_runtime.h>
#include <hip/hip_bf16.h>

#define BB 8
#define SS 4096
#define DD 64
#define QT 64
#define KTILE 128
#define NKT (SS / KTILE)      // 32
#define NTHREADS 512

typedef __attribute__((ext_vector_type(4))) short short4v;
typedef __attribute__((ext_vector_type(8))) short short8v;
typedef __attribute__((ext_vector_type(4))) float float4v;

__device__ __forceinline__ unsigned short f2bf(float f) {
  union { __hip_bfloat16 b; unsigned short u; } cv;
  cv.b = __float2bfloat16(f);
  return cv.u;
}

__device__ __forceinline__ short8v load8(const unsigned short* p) {
  union { short4v h[2]; short8v v; } u;
  u.h[0] = *(const short4v*)p;
  u.h[1] = *(const short4v*)(p + 4);
  return u.v;
}

// Fused masked-softmax attention producing BOTH context and full attn matrix.
// Block = 64 q-rows of one batch. Two sweeps over k:
//   sweep1: QK^T -> exp -> rowsums (mask ballot-packed into LDS bitmask, read once from HBM)
//   sweep2: recompute QK^T -> write normalized attn + PV accumulate (MFMA via LDS P round-trip)
__global__ __launch_bounds__(NTHREADS, 2)
void attn_fused_kernel(const float* __restrict__ Q, const float* __restrict__ K,
                       const float* __restrict__ V, const int* __restrict__ M,
                       float* __restrict__ Octx, float* __restrict__ Oattn) {
  // LDS ~94 KB -> 1 block/CU (8 waves/CU)
  __shared__ __align__(16) unsigned short Qs[QT][72];        // [q][d], pad->72
  __shared__ __align__(16) unsigned short Ks[KTILE][72];     // [kk][d]
  __shared__ __align__(16) unsigned short Vt[DD][KTILE + 8]; // [d][kk] transposed, stride 136 (16B-mult)
  __shared__ __align__(16) unsigned short Ps[QT][KTILE + 8]; // [q][kk] bf16 P tile
  __shared__ unsigned long long Bm[QT * 65];                 // bitmask, row stride 65 u64 (bank stagger)
  __shared__ float RowSum[QT];
  __shared__ float InvRow[QT];

  const int tid  = threadIdx.x;
  const int w    = tid >> 6;
  const int lane = tid & 63;
  const int quad = lane >> 4;
  const int l15  = lane & 15;
  const int qs   = (w & 3) << 4;  // q-strip base (16 rows) for this wave
  const int kh   = (w >> 2) << 6; // kk half (0 or 64) for QK
  const int dh   = (w >> 2) << 5; // d half (0 or 32) for PV

  // batch-per-XCD swizzle: blockIdx round-robins over 8 XCDs -> batch b pinned to one XCD,
  // so that batch's K+V (2 MB) stays in the 4 MB per-XCD L2.
  const int bb = blockIdx.x & 7;
  const int qt = blockIdx.x >> 3;
  const int q0 = qt * QT;

  const float* Qg = Q + ((size_t)bb * SS + q0) * DD;
  const float* Kg = K + (size_t)bb * SS * DD;
  const float* Vg = V + (size_t)bb * SS * DD;
  const int*   Mg = M + ((size_t)bb * SS + q0) * (size_t)SS;
  float* Ag = Oattn + ((size_t)bb * SS + q0) * (size_t)SS;
  float* Cg = Octx + ((size_t)bb * SS + q0) * DD;

  if (tid < QT) RowSum[tid] = 0.f;

  // ---- Q tile -> LDS (bf16) ----
  for (int i = tid; i < QT * 16; i += NTHREADS) {
    const int r = i >> 4, c4 = (i & 15) << 2;
    const float4 qv = *(const float4*)(Qg + (size_t)r * DD + c4);
    short4v pk;
    pk.x = (short)f2bf(qv.x); pk.y = (short)f2bf(qv.y);
    pk.z = (short)f2bf(qv.z); pk.w = (short)f2bf(qv.w);
    *(short4v*)&Qs[r][c4] = pk;
  }

  // ---- mask -> LDS bitmask (single HBM read of the 512 MB mask) ----
  // word layout: Bm[row*65 + (c>>8)*4 + (c&3)], bit index (c>>2)&63
  for (int it = w; it < QT * 16; it += 8) {
    const int r = it >> 4, g = it & 15;
    const int4 m4 = *(const int4*)(Mg + (size_t)r * SS + g * 256 + lane * 4);
    const unsigned long long b0 = __ballot(m4.x != 0);
    const unsigned long long b1 = __ballot(m4.y != 0);
    const unsigned long long b2 = __ballot(m4.z != 0);
    const unsigned long long b3 = __ballot(m4.w != 0);
    if (lane == 0) {
      unsigned long long* dst = &Bm[r * 65 + (g << 2)];
      dst[0] = b0; dst[1] = b1; dst[2] = b2; dst[3] = b3;
    }
  }
  __syncthreads();

  // persistent A-fragments (Q rows for this wave's strip)
  const short8v aq0 = load8(&Qs[qs + l15][quad * 8]);
  const short8v aq1 = load8(&Qs[qs + l15][32 + quad * 8]);

  // ================= sweep 1: row sums =================
  float rsum[4] = {0.f, 0.f, 0.f, 0.f};
  for (int kt = 0; kt < NKT; ++kt) {
    for (int i = tid; i < KTILE * 16; i += NTHREADS) {
      const int r = i >> 4, c4 = (i & 15) << 2;
      const float4 kv = *(const float4*)(Kg + (size_t)(kt * KTILE + r) * DD + c4);
      short4v pk;
      pk.x = (short)f2bf(kv.x); pk.y = (short)f2bf(kv.y);
      pk.z = (short)f2bf(kv.z); pk.w = (short)f2bf(kv.w);
      *(short4v*)&Ks[r][c4] = pk;
    }
    __syncthreads();
#pragma unroll
    for (int t = 0; t < 4; ++t) {
      float4v acc = {0.f, 0.f, 0.f, 0.f};
      const unsigned short* kp = &Ks[kh + t * 16 + l15][quad * 8];
      const short8v b0 = load8(kp);
      const short8v b1 = load8(kp + 32);
      acc = __builtin_amdgcn_mfma_f32_16x16x32_bf16(aq0, b0, acc, 0, 0, 0);
      acc = __builtin_amdgcn_mfma_f32_16x16x32_bf16(aq1, b1, acc, 0, 0, 0);
      const int c = kt * KTILE + kh + t * 16 + l15;
      const int widx = ((c >> 8) << 2) + (c & 3);
      const int bit = (c >> 2) & 63;
#pragma unroll
      for (int r = 0; r < 4; ++r) {
        const int row = qs + quad * 4 + r;
        const bool msk = (Bm[row * 65 + widx] >> bit) & 1ULL;
        const float p = msk ? 0.f : __expf(acc[r] * 0.125f);
        rsum[r] += p;
      }
    }
    __syncthreads();
  }

  // reduce row sums: 16 lanes (l15) share each row; 2 waves share a row -> LDS atomic
#pragma unroll
  for (int r = 0; r < 4; ++r) {
    float v = rsum[r];
    v += __shfl_xor(v, 1);
    v += __shfl_xor(v, 2);
    v += __shfl_xor(v, 4);
    v += __shfl_xor(v, 8);
    if (l15 == 0) atomicAdd(&RowSum[qs + quad * 4 + r], v);
  }
  __syncthreads();
  if (tid < QT) {
    const float s = RowSum[tid];
    InvRow[tid] = (s != 0.f) ? 1.f / s : 0.f;
  }
  __syncthreads();
  float inv[4];
#pragma unroll
  for (int r = 0; r < 4; ++r) inv[r] = InvRow[qs + quad * 4 + r];

  // ================= sweep 2: attn write + PV =================
  float4v cacc0 = {0.f, 0.f, 0.f, 0.f}, cacc1 = {0.f, 0.f, 0.f, 0.f};
  for (int kt = 0; kt < NKT; ++kt) {
    for (int i = tid; i < KTILE * 16; i += NTHREADS) {
      const int r = i >> 4, c4 = (i & 15) << 2;
      const float4 kv = *(const float4*)(Kg + (size_t)(kt * KTILE + r) * DD + c4);
      short4v pk;
      pk.x = (short)f2bf(kv.x); pk.y = (short)f2bf(kv.y);
      pk.z = (short)f2bf(kv.z); pk.w = (short)f2bf(kv.w);
      *(short4v*)&Ks[r][c4] = pk;
    }
    {
      // V tile, stored transposed Vt[d][kk]; per-lane row-sequential global reads (L2-resident)
      const int kk = tid & 127;
      const int d0 = (tid >> 7) << 4;
#pragma unroll
      for (int c4 = 0; c4 < 4; ++c4) {
        const float4 vv = *(const float4*)(Vg + (size_t)(kt * KTILE + kk) * DD + d0 + c4 * 4);
        Vt[d0 + c4 * 4 + 0][kk] = f2bf(vv.x);
        Vt[d0 + c4 * 4 + 1][kk] = f2bf(vv.y);
        Vt[d0 + c4 * 4 + 2][kk] = f2bf(vv.z);
        Vt[d0 + c4 * 4 + 3][kk] = f2bf(vv.w);
      }
    }
    __syncthreads();
#pragma unroll
    for (int t = 0; t < 4; ++t) {
      float4v acc = {0.f, 0.f, 0.f, 0.f};
      const unsigned short* kp = &Ks[kh + t * 16 + l15][quad * 8];
      const short8v b0 = load8(kp);
      const short8v b1 = load8(kp + 32);
      acc = __builtin_amdgcn_mfma_f32_16x16x32_bf16(aq0, b0, acc, 0, 0, 0);
      acc = __builtin_amdgcn_mfma_f32_16x16x32_bf16(aq1, b1, acc, 0, 0, 0);
      const int c = kt * KTILE + kh + t * 16 + l15;
      const int widx = ((c >> 8) << 2) + (c & 3);
      const int bit = (c >> 2) & 63;
#pragma unroll
      for (int r = 0; r < 4; ++r) {
        const int row = qs + quad * 4 + r;
        const bool msk = (Bm[row * 65 + widx] >> bit) & 1ULL;
        const float p = msk ? 0.f : __expf(acc[r] * 0.125f);
        Ps[row][kh + t * 16 + l15] = f2bf(p);         // unnormalized P for PV
        Ag[(size_t)row * SS + c] = p * inv[r];        // normalized attn out (fp32)
      }
    }
    __syncthreads();
    // PV: context[q][d] += P[q][kk] * V[kk][d]
#pragma unroll
    for (int ks = 0; ks < 4; ++ks) {
      const short8v ap = *(const short8v*)&Ps[qs + l15][ks * 32 + quad * 8];
      const short8v bv0 = *(const short8v*)&Vt[dh + l15][ks * 32 + quad * 8];
      const short8v bv1 = *(const short8v*)&Vt[dh + 16 + l15][ks * 32 + quad * 8];
      cacc0 = __builtin_amdgcn_mfma_f32_16x16x32_bf16(ap, bv0, cacc0, 0, 0, 0);
      cacc1 = __builtin_amdgcn_mfma_f32_16x16x32_bf16(ap, bv1, cacc1, 0, 0, 0);
    }
    __syncthreads();
  }

  // context epilogue (normalize at the end)
#pragma unroll
  for (int r = 0; r < 4; ++r) {
    const int row = qs + quad * 4 + r;
    Cg[(size_t)row * DD + dh + l15] = cacc0[r] * inv[r];
    Cg[(size_t)row * DD + dh + 16 + l15] = cacc1[r] * inv[r];
  }
}

extern "C" void kernel_launch(void* const* d_in, const int* in_sizes, int n_in,
                              void* d_out, int out_size, void* d_ws, size_t ws_size,
                              hipStream_t stream) {
  const float* q = (const float*)d_in[0];
  const float* k = (const float*)d_in[1];
  const float* v = (const float*)d_in[2];
  const int*   m = (const int*)d_in[3];
  float* ctx  = (float*)d_out;                        // [B,S,D] first output
  float* attn = (float*)d_out + (size_t)BB * SS * DD; // [B,S,S] second output
  dim3 grid(BB * (SS / QT));  // 512 blocks
  attn_fused_kernel<<<grid, NTHREADS, 0, stream>>>(q, k, v, m, ctx, attn);
}